// Round 1
// baseline (2139.298 us; speedup 1.0000x reference)
//
#include <hip/hip_runtime.h>
#include <math.h>

#define Bq 8
#define Sq 500
#define Tq 30
#define Dq 5
#define Kq 10
#define Hq 64
#define TWq 512
#define Eq 8000
#define NS (Bq*Sq)      // 4000
#define NTt (NS*Dq)     // 20000
#define G3 (3*Hq)       // 192
#define TG 4            // tweet seqs per block
#define BN 16           // bilinear n-tile

__device__ __forceinline__ float sigmoidf_(float x) {
    return 1.0f / (1.0f + expf(-x));
}

__device__ __forceinline__ float wave_sum64(float v) {
    #pragma unroll
    for (int off = 32; off; off >>= 1) v += __shfl_xor(v, off, 64);
    return v;
}

// ---------------- price GRU: one block (192 thr) per sequence ----------------
__global__ __launch_bounds__(192)
void price_gru_kernel(const float* __restrict__ price,
                      const float* __restrict__ Wi, const float* __restrict__ Wh,
                      const float* __restrict__ bi, const float* __restrict__ bh,
                      float* __restrict__ xout) {
    __shared__ __align__(16) float p_s[Tq*3];
    __shared__ __align__(16) float h_s[Hq];
    __shared__ __align__(16) float xg_s[G3];
    __shared__ __align__(16) float hg_s[G3];
    const int n = blockIdx.x;
    const int g = threadIdx.x;            // 0..191
    if (g < Tq*3) p_s[g] = price[(size_t)n*(Tq*3) + g];
    const float wi0 = Wi[0*G3+g], wi1 = Wi[1*G3+g], wi2 = Wi[2*G3+g];
    const float big = bi[g], bhg = bh[g];
    float wh[Hq];
    #pragma unroll
    for (int j = 0; j < Hq; j++) wh[j] = Wh[j*G3 + g];
    if (g < Hq) h_s[g] = 0.0f;
    float hreg = 0.0f, sum = 0.0f;
    __syncthreads();
    for (int t = 0; t < Tq; t++) {
        float xg = big + p_s[t*3+0]*wi0 + p_s[t*3+1]*wi1 + p_s[t*3+2]*wi2;
        float a0=0.f,a1=0.f,a2=0.f,a3=0.f;
        #pragma unroll
        for (int j = 0; j < Hq; j += 4) {
            float4 hv = *(const float4*)&h_s[j];
            a0 = fmaf(hv.x, wh[j+0], a0);
            a1 = fmaf(hv.y, wh[j+1], a1);
            a2 = fmaf(hv.z, wh[j+2], a2);
            a3 = fmaf(hv.w, wh[j+3], a3);
        }
        xg_s[g] = xg;
        hg_s[g] = bhg + ((a0+a1)+(a2+a3));
        __syncthreads();
        if (g < Hq) {
            float r  = sigmoidf_(xg_s[g]      + hg_s[g]);
            float z  = sigmoidf_(xg_s[Hq+g]   + hg_s[Hq+g]);
            float nn = tanhf   (xg_s[2*Hq+g] + r*hg_s[2*Hq+g]);
            hreg = (1.0f - z)*nn + z*hreg;
            sum += hreg;
            h_s[g] = hreg;
        }
        __syncthreads();
    }
    if (g < Hq) xout[(size_t)n*Hq + g] = sum;
}

// ------------- tweet GRU: one block (256 thr) per 4 sequences ---------------
__global__ __launch_bounds__(256)
void tweet_gru_kernel(const float* __restrict__ tweets,
                      const int* __restrict__ counts,
                      const float* __restrict__ Wi, const float* __restrict__ Wh,
                      const float* __restrict__ bi, const float* __restrict__ bh,
                      float* __restrict__ news) {
    __shared__ __align__(16) float x_s[TG][Kq][64];
    __shared__ __align__(16) float xg_acc[TG][Kq][G3];
    __shared__ __align__(16) float h_s[TG][Hq];
    __shared__ __align__(16) float hg_s[TG][G3];
    __shared__ int len_s[TG];
    const int tid = threadIdx.x;
    const int n0 = blockIdx.x * TG;
    const int g = tid;                     // gate column for tid<192
    if (tid < TG) {
        int c = counts[n0 + tid];
        len_s[tid] = c < 0 ? 0 : (c > Kq ? Kq : c);
    }
    if (tid < G3) {
        float b = bi[tid];
        #pragma unroll
        for (int s = 0; s < TG; s++)
            #pragma unroll
            for (int t = 0; t < Kq; t++)
                xg_acc[s][t][tid] = b;
    }
    float w[64];
    for (int kc = 0; kc < TWq/64; kc++) {
        __syncthreads();   // protect x_s from previous iteration's readers
        // stage the 64-wide input chunk for the active (s,t) pairs
        for (int i = tid; i < TG*Kq*16; i += 256) {
            int s  = i / (Kq*16);
            int r  = i - s*(Kq*16);
            int t  = r >> 4;
            int c4 = r & 15;
            if (t < len_s[s]) {
                const float4 v = *(const float4*)&tweets[(((size_t)(n0+s))*Kq + t)*TWq + kc*64 + c4*4];
                *(float4*)&x_s[s][t][c4*4] = v;
            }
        }
        if (tid < G3) {
            #pragma unroll
            for (int c = 0; c < 64; c++) w[c] = Wi[(size_t)(kc*64 + c)*G3 + g];
        }
        __syncthreads();
        if (tid < G3) {
            #pragma unroll
            for (int s = 0; s < TG; s++) {
                const int L = len_s[s];
                for (int t = 0; t < L; t++) {   // block-uniform bound
                    const float* xr = &x_s[s][t][0];
                    float a0=0.f,a1=0.f,a2=0.f,a3=0.f;
                    #pragma unroll
                    for (int c = 0; c < 64; c += 4) {
                        float4 xv = *(const float4*)&xr[c];
                        a0 = fmaf(xv.x, w[c+0], a0);
                        a1 = fmaf(xv.y, w[c+1], a1);
                        a2 = fmaf(xv.z, w[c+2], a2);
                        a3 = fmaf(xv.w, w[c+3], a3);
                    }
                    xg_acc[s][t][g] += ((a0+a1)+(a2+a3));
                }
            }
        }
    }
    // ---- recurrence ----
    if (tid < G3) {
        #pragma unroll
        for (int j = 0; j < Hq; j++) w[j] = Wh[(size_t)j*G3 + g];
    }
    const int su_s = tid >> 6;
    const int su_u = tid & 63;
    h_s[su_s][su_u] = 0.0f;
    const float bhg = (tid < G3) ? bh[g] : 0.0f;
    float hreg = 0.0f, sum = 0.0f;
    __syncthreads();
    for (int t = 0; t < Kq; t++) {
        if (tid < G3) {
            #pragma unroll
            for (int s = 0; s < TG; s++) {
                if (t < len_s[s]) {
                    float a0=0.f,a1=0.f,a2=0.f,a3=0.f;
                    #pragma unroll
                    for (int j = 0; j < Hq; j += 4) {
                        float4 hv = *(const float4*)&h_s[s][j];
                        a0 = fmaf(hv.x, w[j+0], a0);
                        a1 = fmaf(hv.y, w[j+1], a1);
                        a2 = fmaf(hv.z, w[j+2], a2);
                        a3 = fmaf(hv.w, w[j+3], a3);
                    }
                    hg_s[s][g] = bhg + ((a0+a1)+(a2+a3));
                }
            }
        }
        __syncthreads();
        if (t < len_s[su_s]) {
            float r  = sigmoidf_(xg_acc[su_s][t][su_u]        + hg_s[su_s][su_u]);
            float z  = sigmoidf_(xg_acc[su_s][t][Hq+su_u]     + hg_s[su_s][Hq+su_u]);
            float nn = tanhf   (xg_acc[su_s][t][2*Hq+su_u] + r*hg_s[su_s][2*Hq+su_u]);
            hreg = (1.0f - z)*nn + z*hreg;
            sum += hreg;
            h_s[su_s][su_u] = hreg;
        }
        __syncthreads();
    }
    news[(size_t)(n0 + su_s)*Hq + su_u] = sum;
}

// ---------------- date GRU: one block (192 thr) per sequence ----------------
__global__ __launch_bounds__(192)
void date_gru_kernel(const float* __restrict__ news,
                     const float* __restrict__ Wi, const float* __restrict__ Wh,
                     const float* __restrict__ bi, const float* __restrict__ bh,
                     float* __restrict__ text) {
    __shared__ __align__(16) float nw_s[Dq*Hq];
    __shared__ __align__(16) float h_s[Hq];
    __shared__ __align__(16) float xg_s[G3];
    __shared__ __align__(16) float hg_s[G3];
    const int n = blockIdx.x;
    const int g = threadIdx.x;
    for (int i = g; i < Dq*Hq; i += 192) nw_s[i] = news[(size_t)n*Dq*Hq + i];
    float wi[Hq], wh[Hq];
    #pragma unroll
    for (int j = 0; j < Hq; j++) { wi[j] = Wi[j*G3+g]; wh[j] = Wh[j*G3+g]; }
    const float big = bi[g], bhg = bh[g];
    if (g < Hq) h_s[g] = 0.0f;
    float hreg = 0.0f, sum = 0.0f;
    __syncthreads();
    for (int t = 0; t < Dq; t++) {
        float a0=0.f,a1=0.f,a2=0.f,a3=0.f, b0=0.f,b1=0.f,b2=0.f,b3=0.f;
        #pragma unroll
        for (int j = 0; j < Hq; j += 4) {
            float4 nv = *(const float4*)&nw_s[t*Hq + j];
            float4 hv = *(const float4*)&h_s[j];
            a0 = fmaf(nv.x, wi[j+0], a0);
            a1 = fmaf(nv.y, wi[j+1], a1);
            a2 = fmaf(nv.z, wi[j+2], a2);
            a3 = fmaf(nv.w, wi[j+3], a3);
            b0 = fmaf(hv.x, wh[j+0], b0);
            b1 = fmaf(hv.y, wh[j+1], b1);
            b2 = fmaf(hv.z, wh[j+2], b2);
            b3 = fmaf(hv.w, wh[j+3], b3);
        }
        xg_s[g] = big + ((a0+a1)+(a2+a3));
        hg_s[g] = bhg + ((b0+b1)+(b2+b3));
        __syncthreads();
        if (g < Hq) {
            float r  = sigmoidf_(xg_s[g]      + hg_s[g]);
            float z  = sigmoidf_(xg_s[Hq+g]   + hg_s[Hq+g]);
            float nn = tanhf   (xg_s[2*Hq+g] + r*hg_s[2*Hq+g]);
            hreg = (1.0f - z)*nn + z*hreg;
            sum += hreg;
            h_s[g] = hreg;
        }
        __syncthreads();
    }
    if (g < Hq) text[(size_t)n*Hq + g] = sum;
}

// -------- bilinear: comb[n,k] = tanh(text_n . A_k . x_n + b_k) --------------
__global__ __launch_bounds__(256)
void bilinear_kernel(const float* __restrict__ text, const float* __restrict__ x,
                     const float* __restrict__ A, const float* __restrict__ bb,
                     float* __restrict__ ft) {
    __shared__ __align__(16) float t_s[BN*Hq];
    __shared__ __align__(16) float x_s[BN*Hq];
    __shared__ __align__(16) float A_s[Hq*Hq];
    const int tid = threadIdx.x;
    const int nt = blockIdx.x * BN;
    for (int i = tid; i < BN*Hq; i += 256) {
        t_s[i] = text[(size_t)nt*Hq + i];
        x_s[i] = x[(size_t)nt*Hq + i];
    }
    const int nl = tid >> 4;   // 0..15 local row
    const int jl = tid & 15;   // 0..15 j-slice
    __syncthreads();
    const float xv0 = x_s[nl*Hq + jl*4+0];
    const float xv1 = x_s[nl*Hq + jl*4+1];
    const float xv2 = x_s[nl*Hq + jl*4+2];
    const float xv3 = x_s[nl*Hq + jl*4+3];
    for (int k = 0; k < Hq; k++) {
        __syncthreads();       // protect A_s from previous k readers
        for (int i = tid*4; i < Hq*Hq; i += 1024)
            *(float4*)&A_s[i] = *(const float4*)&A[(size_t)k*Hq*Hq + i];
        __syncthreads();
        float acc = 0.0f;
        #pragma unroll 4
        for (int i = 0; i < Hq; i++) {
            float ti = t_s[nl*Hq + i];
            float4 av = *(const float4*)&A_s[i*Hq + jl*4];
            float tmp = av.x*xv0 + av.y*xv1;
            tmp = fmaf(av.z, xv2, tmp);
            tmp = fmaf(av.w, xv3, tmp);
            acc = fmaf(ti, tmp, acc);
        }
        #pragma unroll
        for (int off = 8; off; off >>= 1) acc += __shfl_xor(acc, off, 16);
        if (jl == 0) ft[(size_t)(nt+nl)*Hq + k] = tanhf(acc + bb[k]);
    }
}

// ----------------------------- GNN ------------------------------------------
__global__ void deg_kernel(const int* __restrict__ ei, float* __restrict__ deg) {
    int e = blockIdx.x*256 + threadIdx.x;
    if (e < Eq) atomicAdd(&deg[ei[Eq + e]], 1.0f);
}

__global__ void agg_kernel(const int* __restrict__ ei, const float* __restrict__ ft,
                           float* __restrict__ agg) {
    int gid = blockIdx.x*256 + threadIdx.x;
    int e = gid >> 6;
    int u = gid & 63;
    if (e < Eq) {
        int src = ei[e], dst = ei[Eq + e];
        #pragma unroll
        for (int b = 0; b < Bq; b++) {
            atomicAdd(&agg[((size_t)(b*Sq + dst))*Hq + u],
                      ft[((size_t)(b*Sq + src))*Hq + u]);
        }
    }
}

// ------------------------------ head ----------------------------------------
__global__ __launch_bounds__(64)
void head_kernel(const float* __restrict__ ft, const float* __restrict__ agg,
                 const float* __restrict__ deg,
                 const float* __restrict__ gnn_W, const float* __restrict__ gnn_b,
                 const float* __restrict__ fc1_W, const float* __restrict__ fc1_b,
                 const float* __restrict__ ln1_g, const float* __restrict__ ln1_b,
                 const float* __restrict__ fc2_W, const float* __restrict__ fc2_b,
                 const float* __restrict__ ln2_g, const float* __restrict__ ln2_b,
                 const float* __restrict__ mlp_W1, const float* __restrict__ mlp_b1,
                 const float* __restrict__ mlp_W2, const float* __restrict__ mlp_b2,
                 float* __restrict__ out) {
    __shared__ __align__(16) float a_s[Hq];
    __shared__ __align__(16) float in_s[2*Hq];
    __shared__ __align__(16) float t_s[Hq];
    const int n = blockIdx.x;
    const int s = n % Sq;
    const int u = threadIdx.x;
    const float denom = fmaxf(deg[s], 1.0f);
    a_s[u]  = agg[(size_t)n*Hq + u] / denom;
    in_s[u] = ft[(size_t)n*Hq + u];
    __syncthreads();
    // gnn linear + tanh
    {
        float a0=0.f,a1=0.f,a2=0.f,a3=0.f;
        #pragma unroll
        for (int j = 0; j < Hq; j += 4) {
            a0 = fmaf(a_s[j+0], gnn_W[(j+0)*Hq + u], a0);
            a1 = fmaf(a_s[j+1], gnn_W[(j+1)*Hq + u], a1);
            a2 = fmaf(a_s[j+2], gnn_W[(j+2)*Hq + u], a2);
            a3 = fmaf(a_s[j+3], gnn_W[(j+3)*Hq + u], a3);
        }
        in_s[Hq+u] = tanhf(gnn_b[u] + ((a0+a1)+(a2+a3)));
    }
    __syncthreads();
    // fc1 + LN + relu
    float v;
    {
        float a0=0.f,a1=0.f,a2=0.f,a3=0.f;
        #pragma unroll
        for (int j = 0; j < 2*Hq; j += 4) {
            a0 = fmaf(in_s[j+0], fc1_W[(j+0)*Hq + u], a0);
            a1 = fmaf(in_s[j+1], fc1_W[(j+1)*Hq + u], a1);
            a2 = fmaf(in_s[j+2], fc1_W[(j+2)*Hq + u], a2);
            a3 = fmaf(in_s[j+3], fc1_W[(j+3)*Hq + u], a3);
        }
        v = fc1_b[u] + ((a0+a1)+(a2+a3));
        float m = wave_sum64(v) * (1.0f/Hq);
        float d = v - m;
        float var = wave_sum64(d*d) * (1.0f/Hq);
        v = fmaxf(d * rsqrtf(var + 1e-5f) * ln1_g[u] + ln1_b[u], 0.0f);
    }
    t_s[u] = v;
    __syncthreads();
    // fc2 + LN + relu
    {
        float a0=0.f,a1=0.f,a2=0.f,a3=0.f;
        #pragma unroll
        for (int j = 0; j < Hq; j += 4) {
            a0 = fmaf(t_s[j+0], fc2_W[(j+0)*Hq + u], a0);
            a1 = fmaf(t_s[j+1], fc2_W[(j+1)*Hq + u], a1);
            a2 = fmaf(t_s[j+2], fc2_W[(j+2)*Hq + u], a2);
            a3 = fmaf(t_s[j+3], fc2_W[(j+3)*Hq + u], a3);
        }
        v = fc2_b[u] + ((a0+a1)+(a2+a3));
        float m = wave_sum64(v) * (1.0f/Hq);
        float d = v - m;
        float var = wave_sum64(d*d) * (1.0f/Hq);
        v = fmaxf(d * rsqrtf(var + 1e-5f) * ln2_g[u] + ln2_b[u], 0.0f);
    }
    __syncthreads();
    a_s[u] = v;          // reuse a_s for mlp input
    __syncthreads();
    // mlp layer 1 + relu
    {
        float a0=0.f,a1=0.f,a2=0.f,a3=0.f;
        #pragma unroll
        for (int j = 0; j < Hq; j += 4) {
            a0 = fmaf(a_s[j+0], mlp_W1[(j+0)*Hq + u], a0);
            a1 = fmaf(a_s[j+1], mlp_W1[(j+1)*Hq + u], a1);
            a2 = fmaf(a_s[j+2], mlp_W1[(j+2)*Hq + u], a2);
            a3 = fmaf(a_s[j+3], mlp_W1[(j+3)*Hq + u], a3);
        }
        v = fmaxf(mlp_b1[u] + ((a0+a1)+(a2+a3)), 0.0f);
    }
    // final projection to scalar
    float p = wave_sum64(v * mlp_W2[u]);
    if (u == 0) out[n] = p + mlp_b2[0];
}

extern "C" void kernel_launch(void* const* d_in, const int* in_sizes, int n_in,
                              void* d_out, int out_size, void* d_ws, size_t ws_size,
                              hipStream_t stream) {
    (void)in_sizes; (void)n_in; (void)out_size; (void)ws_size;
    const float* price  = (const float*)d_in[0];
    const float* tweets = (const float*)d_in[1];
    const int*   counts = (const int*)d_in[2];
    const int*   ei     = (const int*)d_in[3];
    // d_in[4] = num_edge_type (unused)
    const float* pg_Wi = (const float*)d_in[5];
    const float* pg_Wh = (const float*)d_in[6];
    const float* pg_bi = (const float*)d_in[7];
    const float* pg_bh = (const float*)d_in[8];
    const float* tg_Wi = (const float*)d_in[9];
    const float* tg_Wh = (const float*)d_in[10];
    const float* tg_bi = (const float*)d_in[11];
    const float* tg_bh = (const float*)d_in[12];
    const float* dg_Wi = (const float*)d_in[13];
    const float* dg_Wh = (const float*)d_in[14];
    const float* dg_bi = (const float*)d_in[15];
    const float* dg_bh = (const float*)d_in[16];
    const float* bil_A = (const float*)d_in[17];
    const float* bil_b = (const float*)d_in[18];
    const float* gnn_W = (const float*)d_in[19];
    const float* gnn_b = (const float*)d_in[20];
    const float* fc1_W = (const float*)d_in[21];
    const float* fc1_b = (const float*)d_in[22];
    const float* ln1_g = (const float*)d_in[23];
    const float* ln1_b = (const float*)d_in[24];
    const float* fc2_W = (const float*)d_in[25];
    const float* fc2_b = (const float*)d_in[26];
    const float* ln2_g = (const float*)d_in[27];
    const float* ln2_b = (const float*)d_in[28];
    const float* mlp_W1 = (const float*)d_in[29];
    const float* mlp_b1 = (const float*)d_in[30];
    const float* mlp_W2 = (const float*)d_in[31];
    const float* mlp_b2 = (const float*)d_in[32];

    float* ws      = (float*)d_ws;
    float* x_price = ws;                   // 4000*64   = 256000
    float* news    = ws + 256000;          // 20000*64  = 1280000
    float* text    = ws + 1536000;         // 4000*64
    float* ft      = ws + 1792000;         // 4000*64
    float* agg     = ws + 2048000;         // 8*500*64  = 256000
    float* deg     = ws + 2304000;         // 512

    hipMemsetAsync(agg, 0, (256000 + 512)*sizeof(float), stream);

    price_gru_kernel<<<NS, 192, 0, stream>>>(price, pg_Wi, pg_Wh, pg_bi, pg_bh, x_price);
    tweet_gru_kernel<<<NTt/TG, 256, 0, stream>>>(tweets, counts, tg_Wi, tg_Wh, tg_bi, tg_bh, news);
    date_gru_kernel<<<NS, 192, 0, stream>>>(news, dg_Wi, dg_Wh, dg_bi, dg_bh, text);
    bilinear_kernel<<<NS/BN, 256, 0, stream>>>(text, x_price, bil_A, bil_b, ft);
    deg_kernel<<<(Eq+255)/256, 256, 0, stream>>>(ei, deg);
    agg_kernel<<<(Eq*Hq)/256, 256, 0, stream>>>(ei, ft, agg);
    head_kernel<<<NS, 64, 0, stream>>>(ft, agg, deg,
                                       gnn_W, gnn_b, fc1_W, fc1_b, ln1_g, ln1_b,
                                       fc2_W, fc2_b, ln2_g, ln2_b,
                                       mlp_W1, mlp_b1, mlp_W2, mlp_b2,
                                       (float*)d_out);
}

// Round 2
// 1250.627 us; speedup vs baseline: 1.7106x; 1.7106x over previous
//
#include <hip/hip_runtime.h>
#include <math.h>

#define Bq 8
#define Sq 500
#define Tq 30
#define Dq 5
#define Kq 10
#define Hq 64
#define TWq 512
#define Eq 8000
#define NS (Bq*Sq)      // 4000
#define NTt (NS*Dq)     // 20000
#define G3 (3*Hq)       // 192
#define TG 4            // tweet seqs per block
#define BN 16           // bilinear n-tile

#define MR 48           // padded GEMM rows (TG*Kq=40 -> 48)
#define KC 64           // K chunk staged per iteration
#define XPITCH 72       // LDS row pitch in bf16 elems (144B: 2-way bank alias = free)
#define NKT (TWq/32)    // 16 k-tiles of 32
#define NNT (G3/16)     // 12 n-tiles of 16

typedef __attribute__((ext_vector_type(8))) short short8_t;
typedef __attribute__((ext_vector_type(4))) float float4_t;

__device__ __forceinline__ float sigmoidf_(float x) {
    return 1.0f / (1.0f + expf(-x));
}

__device__ __forceinline__ float wave_sum64(float v) {
    #pragma unroll
    for (int off = 32; off; off >>= 1) v += __shfl_xor(v, off, 64);
    return v;
}

__device__ __forceinline__ short f32_to_bf16_rn(float f) {
    union { float f; unsigned u; } v; v.f = f;
    unsigned r = v.u + 0x7fffu + ((v.u >> 16) & 1u);
    return (short)(r >> 16);
}
__device__ __forceinline__ float bf16_to_f32(short s) {
    union { unsigned u; float f; } v; v.u = ((unsigned)(unsigned short)s) << 16;
    return v.f;
}

// ---- precompute tg_Wi into MFMA B-fragment order, split hi/lo bf16 --------
// Wf[kt][nt][lane][j] = W[kt*32 + (lane>>4)*8 + j][nt*16 + (lane&15)]
__global__ __launch_bounds__(64)
void wfrag_prep_kernel(const float* __restrict__ Wi,
                       short* __restrict__ Wf_hi, short* __restrict__ Wf_lo) {
    const int kt = blockIdx.x / NNT;
    const int nt = blockIdx.x - kt*NNT;
    const int lane = threadIdx.x;
    const int quad = lane >> 4, l16 = lane & 15;
    short h[8], l[8];
    #pragma unroll
    for (int j = 0; j < 8; j++) {
        int k = kt*32 + quad*8 + j;
        int n = nt*16 + l16;
        float w = Wi[(size_t)k*G3 + n];
        short hi = f32_to_bf16_rn(w);
        short lo = f32_to_bf16_rn(w - bf16_to_f32(hi));
        h[j] = hi; l[j] = lo;
    }
    size_t off = ((size_t)blockIdx.x*64 + lane)*8;
    *(short8_t*)(Wf_hi + off) = *(const short8_t*)h;
    *(short8_t*)(Wf_lo + off) = *(const short8_t*)l;
}

// ---------------- price GRU: one block (192 thr) per sequence ----------------
__global__ __launch_bounds__(192)
void price_gru_kernel(const float* __restrict__ price,
                      const float* __restrict__ Wi, const float* __restrict__ Wh,
                      const float* __restrict__ bi, const float* __restrict__ bh,
                      float* __restrict__ xout) {
    __shared__ __align__(16) float p_s[Tq*3];
    __shared__ __align__(16) float h_s[Hq];
    __shared__ __align__(16) float xg_s[G3];
    __shared__ __align__(16) float hg_s[G3];
    const int n = blockIdx.x;
    const int g = threadIdx.x;            // 0..191
    if (g < Tq*3) p_s[g] = price[(size_t)n*(Tq*3) + g];
    const float wi0 = Wi[0*G3+g], wi1 = Wi[1*G3+g], wi2 = Wi[2*G3+g];
    const float big = bi[g], bhg = bh[g];
    float wh[Hq];
    #pragma unroll
    for (int j = 0; j < Hq; j++) wh[j] = Wh[j*G3 + g];
    if (g < Hq) h_s[g] = 0.0f;
    float hreg = 0.0f, sum = 0.0f;
    __syncthreads();
    for (int t = 0; t < Tq; t++) {
        float xg = big + p_s[t*3+0]*wi0 + p_s[t*3+1]*wi1 + p_s[t*3+2]*wi2;
        float a0=0.f,a1=0.f,a2=0.f,a3=0.f;
        #pragma unroll
        for (int j = 0; j < Hq; j += 4) {
            float4 hv = *(const float4*)&h_s[j];
            a0 = fmaf(hv.x, wh[j+0], a0);
            a1 = fmaf(hv.y, wh[j+1], a1);
            a2 = fmaf(hv.z, wh[j+2], a2);
            a3 = fmaf(hv.w, wh[j+3], a3);
        }
        xg_s[g] = xg;
        hg_s[g] = bhg + ((a0+a1)+(a2+a3));
        __syncthreads();
        if (g < Hq) {
            float r  = sigmoidf_(xg_s[g]      + hg_s[g]);
            float z  = sigmoidf_(xg_s[Hq+g]   + hg_s[Hq+g]);
            float nn = tanhf   (xg_s[2*Hq+g] + r*hg_s[2*Hq+g]);
            hreg = (1.0f - z)*nn + z*hreg;
            sum += hreg;
            h_s[g] = hreg;
        }
        __syncthreads();
    }
    if (g < Hq) xout[(size_t)n*Hq + g] = sum;
}

// ------------- tweet GRU: MFMA split-bf16 projection + fp32 recurrence ------
// block: 256 thr (4 waves), TG=4 sequences, M=40 rows padded to 48.
__global__ __launch_bounds__(256)
void tweet_gru_kernel(const float* __restrict__ tweets,
                      const int* __restrict__ counts,
                      const short* __restrict__ Wf_hi, const short* __restrict__ Wf_lo,
                      const float* __restrict__ Wh,
                      const float* __restrict__ bi, const float* __restrict__ bh,
                      float* __restrict__ news) {
    // smem: during GEMM, x_hi/x_lo staging (13.8 KB); after, xg[48][192] fp32 (36.9 KB)
    __shared__ __align__(16) char smem[MR*G3*4];
    __shared__ __align__(16) float h_s[TG][Hq];
    __shared__ __align__(16) float hg_s[TG][G3];
    __shared__ int len_s[TG];
    short* x_hi = (short*)smem;                       // MR*XPITCH = 3456 shorts
    short* x_lo = (short*)(smem + MR*XPITCH*2);
    float* xg   = (float*)smem;                       // aliases staging (used after)

    const int tid  = threadIdx.x;
    const int n0   = blockIdx.x * TG;
    const int wave = tid >> 6;
    const int lane = tid & 63;
    const int quad = lane >> 4;
    const int l16  = lane & 15;

    if (tid < TG) {
        int c = counts[n0 + tid];
        len_s[tid] = c < 0 ? 0 : (c > Kq ? Kq : c);
    }

    float4_t acc[3][3];   // [mt][ntl]
    #pragma unroll
    for (int a = 0; a < 3; a++)
        #pragma unroll
        for (int b = 0; b < 3; b++)
            acc[a][b] = (float4_t){0.f, 0.f, 0.f, 0.f};

    for (int ch = 0; ch < TWq/KC; ch++) {
        __syncthreads();   // previous chunk's A-frag readers done
        // stage active rows: 40 rows x 16 float4
        for (int i = tid; i < TG*Kq*(KC/4); i += 256) {
            int row = i >> 4;
            int c4  = i & 15;
            int s   = (row*205) >> 11;       // row/10 for row<48
            int t   = row - s*10;
            if (t < len_s[s]) {
                float4 v = *(const float4*)&tweets[(((size_t)(n0+s))*Kq + t)*TWq + ch*KC + c4*4];
                short hh[4], ll[4];
                float f[4] = {v.x, v.y, v.z, v.w};
                #pragma unroll
                for (int j = 0; j < 4; j++) {
                    short hi = f32_to_bf16_rn(f[j]);
                    hh[j] = hi;
                    ll[j] = f32_to_bf16_rn(f[j] - bf16_to_f32(hi));
                }
                *(short4*)&x_hi[row*XPITCH + c4*4] = *(const short4*)hh;
                *(short4*)&x_lo[row*XPITCH + c4*4] = *(const short4*)ll;
            }
        }
        __syncthreads();
        #pragma unroll
        for (int ks = 0; ks < KC/32; ks++) {
            const int kt = ch*(KC/32) + ks;
            short8_t bh_[3], bl_[3];
            #pragma unroll
            for (int ntl = 0; ntl < 3; ntl++) {
                size_t off = (((size_t)kt*NNT + (wave*3 + ntl))*64 + lane)*8;
                bh_[ntl] = *(const short8_t*)(Wf_hi + off);
                bl_[ntl] = *(const short8_t*)(Wf_lo + off);
            }
            short8_t ah_[3], al_[3];
            #pragma unroll
            for (int mt = 0; mt < 3; mt++) {
                int addr = (mt*16 + l16)*XPITCH + ks*32 + quad*8;
                ah_[mt] = *(const short8_t*)&x_hi[addr];
                al_[mt] = *(const short8_t*)&x_lo[addr];
            }
            #pragma unroll
            for (int mt = 0; mt < 3; mt++)
                #pragma unroll
                for (int ntl = 0; ntl < 3; ntl++) {
                    acc[mt][ntl] = __builtin_amdgcn_mfma_f32_16x16x32_bf16(ah_[mt], bh_[ntl], acc[mt][ntl], 0, 0, 0);
                    acc[mt][ntl] = __builtin_amdgcn_mfma_f32_16x16x32_bf16(ah_[mt], bl_[ntl], acc[mt][ntl], 0, 0, 0);
                    acc[mt][ntl] = __builtin_amdgcn_mfma_f32_16x16x32_bf16(al_[mt], bh_[ntl], acc[mt][ntl], 0, 0, 0);
                }
        }
    }
    __syncthreads();       // all A-frag reads done before xg overwrites staging
    // epilogue: acc -> xg LDS (+bias).  C layout: col=lane&15, row=quad*4+reg
    #pragma unroll
    for (int ntl = 0; ntl < 3; ntl++) {
        const int col = (wave*3 + ntl)*16 + l16;
        const float bic = bi[col];
        #pragma unroll
        for (int mt = 0; mt < 3; mt++) {
            const int row0 = mt*16 + quad*4;
            #pragma unroll
            for (int r = 0; r < 4; r++)
                xg[(row0 + r)*G3 + col] = acc[mt][ntl][r] + bic;
        }
    }
    // ---- recurrence (fp32) ----
    const int g = tid;
    float w[Hq];
    if (tid < G3) {
        #pragma unroll
        for (int j = 0; j < Hq; j++) w[j] = Wh[(size_t)j*G3 + g];
    }
    const float bhg = (tid < G3) ? bh[g] : 0.0f;
    const int su_s = tid >> 6;
    const int su_u = tid & 63;
    h_s[su_s][su_u] = 0.0f;
    float hreg = 0.0f, sum = 0.0f;
    __syncthreads();
    for (int t = 0; t < Kq; t++) {
        if (tid < G3) {
            #pragma unroll
            for (int s = 0; s < TG; s++) {
                if (t < len_s[s]) {
                    float a0=0.f,a1=0.f,a2=0.f,a3=0.f;
                    #pragma unroll
                    for (int j = 0; j < Hq; j += 4) {
                        float4 hv = *(const float4*)&h_s[s][j];
                        a0 = fmaf(hv.x, w[j+0], a0);
                        a1 = fmaf(hv.y, w[j+1], a1);
                        a2 = fmaf(hv.z, w[j+2], a2);
                        a3 = fmaf(hv.w, w[j+3], a3);
                    }
                    hg_s[s][g] = bhg + ((a0+a1)+(a2+a3));
                }
            }
        }
        __syncthreads();
        if (t < len_s[su_s]) {
            const float* xr = &xg[(su_s*Kq + t)*G3];
            float r  = sigmoidf_(xr[su_u]        + hg_s[su_s][su_u]);
            float z  = sigmoidf_(xr[Hq+su_u]     + hg_s[su_s][Hq+su_u]);
            float nn = tanhf   (xr[2*Hq+su_u] + r*hg_s[su_s][2*Hq+su_u]);
            hreg = (1.0f - z)*nn + z*hreg;
            sum += hreg;
            h_s[su_s][su_u] = hreg;
        }
        __syncthreads();
    }
    news[(size_t)(n0 + su_s)*Hq + su_u] = sum;
}

// ---------------- date GRU: one block (192 thr) per sequence ----------------
__global__ __launch_bounds__(192)
void date_gru_kernel(const float* __restrict__ news,
                     const float* __restrict__ Wi, const float* __restrict__ Wh,
                     const float* __restrict__ bi, const float* __restrict__ bh,
                     float* __restrict__ text) {
    __shared__ __align__(16) float nw_s[Dq*Hq];
    __shared__ __align__(16) float h_s[Hq];
    __shared__ __align__(16) float xg_s[G3];
    __shared__ __align__(16) float hg_s[G3];
    const int n = blockIdx.x;
    const int g = threadIdx.x;
    for (int i = g; i < Dq*Hq; i += 192) nw_s[i] = news[(size_t)n*Dq*Hq + i];
    float wi[Hq], wh[Hq];
    #pragma unroll
    for (int j = 0; j < Hq; j++) { wi[j] = Wi[j*G3+g]; wh[j] = Wh[j*G3+g]; }
    const float big = bi[g], bhg = bh[g];
    if (g < Hq) h_s[g] = 0.0f;
    float hreg = 0.0f, sum = 0.0f;
    __syncthreads();
    for (int t = 0; t < Dq; t++) {
        float a0=0.f,a1=0.f,a2=0.f,a3=0.f, b0=0.f,b1=0.f,b2=0.f,b3=0.f;
        #pragma unroll
        for (int j = 0; j < Hq; j += 4) {
            float4 nv = *(const float4*)&nw_s[t*Hq + j];
            float4 hv = *(const float4*)&h_s[j];
            a0 = fmaf(nv.x, wi[j+0], a0);
            a1 = fmaf(nv.y, wi[j+1], a1);
            a2 = fmaf(nv.z, wi[j+2], a2);
            a3 = fmaf(nv.w, wi[j+3], a3);
            b0 = fmaf(hv.x, wh[j+0], b0);
            b1 = fmaf(hv.y, wh[j+1], b1);
            b2 = fmaf(hv.z, wh[j+2], b2);
            b3 = fmaf(hv.w, wh[j+3], b3);
        }
        xg_s[g] = big + ((a0+a1)+(a2+a3));
        hg_s[g] = bhg + ((b0+b1)+(b2+b3));
        __syncthreads();
        if (g < Hq) {
            float r  = sigmoidf_(xg_s[g]      + hg_s[g]);
            float z  = sigmoidf_(xg_s[Hq+g]   + hg_s[Hq+g]);
            float nn = tanhf   (xg_s[2*Hq+g] + r*hg_s[2*Hq+g]);
            hreg = (1.0f - z)*nn + z*hreg;
            sum += hreg;
            h_s[g] = hreg;
        }
        __syncthreads();
    }
    if (g < Hq) text[(size_t)n*Hq + g] = sum;
}

// -------- bilinear: comb[n,k] = tanh(text_n . A_k . x_n + b_k) --------------
__global__ __launch_bounds__(256)
void bilinear_kernel(const float* __restrict__ text, const float* __restrict__ x,
                     const float* __restrict__ A, const float* __restrict__ bb,
                     float* __restrict__ ft) {
    __shared__ __align__(16) float t_s[BN*Hq];
    __shared__ __align__(16) float x_s[BN*Hq];
    __shared__ __align__(16) float A_s[Hq*Hq];
    const int tid = threadIdx.x;
    const int nt = blockIdx.x * BN;
    for (int i = tid; i < BN*Hq; i += 256) {
        t_s[i] = text[(size_t)nt*Hq + i];
        x_s[i] = x[(size_t)nt*Hq + i];
    }
    const int nl = tid >> 4;   // 0..15 local row
    const int jl = tid & 15;   // 0..15 j-slice
    __syncthreads();
    const float xv0 = x_s[nl*Hq + jl*4+0];
    const float xv1 = x_s[nl*Hq + jl*4+1];
    const float xv2 = x_s[nl*Hq + jl*4+2];
    const float xv3 = x_s[nl*Hq + jl*4+3];
    for (int k = 0; k < Hq; k++) {
        __syncthreads();       // protect A_s from previous k readers
        for (int i = tid*4; i < Hq*Hq; i += 1024)
            *(float4*)&A_s[i] = *(const float4*)&A[(size_t)k*Hq*Hq + i];
        __syncthreads();
        float acc = 0.0f;
        #pragma unroll 4
        for (int i = 0; i < Hq; i++) {
            float ti = t_s[nl*Hq + i];
            float4 av = *(const float4*)&A_s[i*Hq + jl*4];
            float tmp = av.x*xv0 + av.y*xv1;
            tmp = fmaf(av.z, xv2, tmp);
            tmp = fmaf(av.w, xv3, tmp);
            acc = fmaf(ti, tmp, acc);
        }
        #pragma unroll
        for (int off = 8; off; off >>= 1) acc += __shfl_xor(acc, off, 16);
        if (jl == 0) ft[(size_t)(nt+nl)*Hq + k] = tanhf(acc + bb[k]);
    }
}

// ----------------------------- GNN ------------------------------------------
__global__ void deg_kernel(const int* __restrict__ ei, float* __restrict__ deg) {
    int e = blockIdx.x*256 + threadIdx.x;
    if (e < Eq) atomicAdd(&deg[ei[Eq + e]], 1.0f);
}

__global__ void agg_kernel(const int* __restrict__ ei, const float* __restrict__ ft,
                           float* __restrict__ agg) {
    int gid = blockIdx.x*256 + threadIdx.x;
    int e = gid >> 6;
    int u = gid & 63;
    if (e < Eq) {
        int src = ei[e], dst = ei[Eq + e];
        #pragma unroll
        for (int b = 0; b < Bq; b++) {
            atomicAdd(&agg[((size_t)(b*Sq + dst))*Hq + u],
                      ft[((size_t)(b*Sq + src))*Hq + u]);
        }
    }
}

// ------------------------------ head ----------------------------------------
__global__ __launch_bounds__(64)
void head_kernel(const float* __restrict__ ft, const float* __restrict__ agg,
                 const float* __restrict__ deg,
                 const float* __restrict__ gnn_W, const float* __restrict__ gnn_b,
                 const float* __restrict__ fc1_W, const float* __restrict__ fc1_b,
                 const float* __restrict__ ln1_g, const float* __restrict__ ln1_b,
                 const float* __restrict__ fc2_W, const float* __restrict__ fc2_b,
                 const float* __restrict__ ln2_g, const float* __restrict__ ln2_b,
                 const float* __restrict__ mlp_W1, const float* __restrict__ mlp_b1,
                 const float* __restrict__ mlp_W2, const float* __restrict__ mlp_b2,
                 float* __restrict__ out) {
    __shared__ __align__(16) float a_s[Hq];
    __shared__ __align__(16) float in_s[2*Hq];
    __shared__ __align__(16) float t_s[Hq];
    const int n = blockIdx.x;
    const int s = n % Sq;
    const int u = threadIdx.x;
    const float denom = fmaxf(deg[s], 1.0f);
    a_s[u]  = agg[(size_t)n*Hq + u] / denom;
    in_s[u] = ft[(size_t)n*Hq + u];
    __syncthreads();
    // gnn linear + tanh
    {
        float a0=0.f,a1=0.f,a2=0.f,a3=0.f;
        #pragma unroll
        for (int j = 0; j < Hq; j += 4) {
            a0 = fmaf(a_s[j+0], gnn_W[(j+0)*Hq + u], a0);
            a1 = fmaf(a_s[j+1], gnn_W[(j+1)*Hq + u], a1);
            a2 = fmaf(a_s[j+2], gnn_W[(j+2)*Hq + u], a2);
            a3 = fmaf(a_s[j+3], gnn_W[(j+3)*Hq + u], a3);
        }
        in_s[Hq+u] = tanhf(gnn_b[u] + ((a0+a1)+(a2+a3)));
    }
    __syncthreads();
    // fc1 + LN + relu
    float v;
    {
        float a0=0.f,a1=0.f,a2=0.f,a3=0.f;
        #pragma unroll
        for (int j = 0; j < 2*Hq; j += 4) {
            a0 = fmaf(in_s[j+0], fc1_W[(j+0)*Hq + u], a0);
            a1 = fmaf(in_s[j+1], fc1_W[(j+1)*Hq + u], a1);
            a2 = fmaf(in_s[j+2], fc1_W[(j+2)*Hq + u], a2);
            a3 = fmaf(in_s[j+3], fc1_W[(j+3)*Hq + u], a3);
        }
        v = fc1_b[u] + ((a0+a1)+(a2+a3));
        float m = wave_sum64(v) * (1.0f/Hq);
        float d = v - m;
        float var = wave_sum64(d*d) * (1.0f/Hq);
        v = fmaxf(d * rsqrtf(var + 1e-5f) * ln1_g[u] + ln1_b[u], 0.0f);
    }
    t_s[u] = v;
    __syncthreads();
    // fc2 + LN + relu
    {
        float a0=0.f,a1=0.f,a2=0.f,a3=0.f;
        #pragma unroll
        for (int j = 0; j < Hq; j += 4) {
            a0 = fmaf(t_s[j+0], fc2_W[(j+0)*Hq + u], a0);
            a1 = fmaf(t_s[j+1], fc2_W[(j+1)*Hq + u], a1);
            a2 = fmaf(t_s[j+2], fc2_W[(j+2)*Hq + u], a2);
            a3 = fmaf(t_s[j+3], fc2_W[(j+3)*Hq + u], a3);
        }
        v = fc2_b[u] + ((a0+a1)+(a2+a3));
        float m = wave_sum64(v) * (1.0f/Hq);
        float d = v - m;
        float var = wave_sum64(d*d) * (1.0f/Hq);
        v = fmaxf(d * rsqrtf(var + 1e-5f) * ln2_g[u] + ln2_b[u], 0.0f);
    }
    __syncthreads();
    a_s[u] = v;          // reuse a_s for mlp input
    __syncthreads();
    // mlp layer 1 + relu
    {
        float a0=0.f,a1=0.f,a2=0.f,a3=0.f;
        #pragma unroll
        for (int j = 0; j < Hq; j += 4) {
            a0 = fmaf(a_s[j+0], mlp_W1[(j+0)*Hq + u], a0);
            a1 = fmaf(a_s[j+1], mlp_W1[(j+1)*Hq + u], a1);
            a2 = fmaf(a_s[j+2], mlp_W1[(j+2)*Hq + u], a2);
            a3 = fmaf(a_s[j+3], mlp_W1[(j+3)*Hq + u], a3);
        }
        v = fmaxf(mlp_b1[u] + ((a0+a1)+(a2+a3)), 0.0f);
    }
    // final projection to scalar
    float p = wave_sum64(v * mlp_W2[u]);
    if (u == 0) out[n] = p + mlp_b2[0];
}

extern "C" void kernel_launch(void* const* d_in, const int* in_sizes, int n_in,
                              void* d_out, int out_size, void* d_ws, size_t ws_size,
                              hipStream_t stream) {
    (void)in_sizes; (void)n_in; (void)out_size; (void)ws_size;
    const float* price  = (const float*)d_in[0];
    const float* tweets = (const float*)d_in[1];
    const int*   counts = (const int*)d_in[2];
    const int*   ei     = (const int*)d_in[3];
    // d_in[4] = num_edge_type (unused)
    const float* pg_Wi = (const float*)d_in[5];
    const float* pg_Wh = (const float*)d_in[6];
    const float* pg_bi = (const float*)d_in[7];
    const float* pg_bh = (const float*)d_in[8];
    const float* tg_Wi = (const float*)d_in[9];
    const float* tg_Wh = (const float*)d_in[10];
    const float* tg_bi = (const float*)d_in[11];
    const float* tg_bh = (const float*)d_in[12];
    const float* dg_Wi = (const float*)d_in[13];
    const float* dg_Wh = (const float*)d_in[14];
    const float* dg_bi = (const float*)d_in[15];
    const float* dg_bh = (const float*)d_in[16];
    const float* bil_A = (const float*)d_in[17];
    const float* bil_b = (const float*)d_in[18];
    const float* gnn_W = (const float*)d_in[19];
    const float* gnn_b = (const float*)d_in[20];
    const float* fc1_W = (const float*)d_in[21];
    const float* fc1_b = (const float*)d_in[22];
    const float* ln1_g = (const float*)d_in[23];
    const float* ln1_b = (const float*)d_in[24];
    const float* fc2_W = (const float*)d_in[25];
    const float* fc2_b = (const float*)d_in[26];
    const float* ln2_g = (const float*)d_in[27];
    const float* ln2_b = (const float*)d_in[28];
    const float* mlp_W1 = (const float*)d_in[29];
    const float* mlp_b1 = (const float*)d_in[30];
    const float* mlp_W2 = (const float*)d_in[31];
    const float* mlp_b2 = (const float*)d_in[32];

    float* ws      = (float*)d_ws;
    float* x_price = ws;                   // 4000*64   = 256000
    float* news    = ws + 256000;          // 20000*64  = 1280000
    float* text    = ws + 1536000;         // 4000*64
    float* ft      = ws + 1792000;         // 4000*64
    float* agg     = ws + 2048000;         // 8*500*64  = 256000
    float* deg     = ws + 2304000;         // 512
    short* Wf_hi   = (short*)(ws + 2304512);              // 98304 shorts
    short* Wf_lo   = (short*)((char*)Wf_hi + NKT*NNT*64*8*sizeof(short));

    hipMemsetAsync(agg, 0, (256000 + 512)*sizeof(float), stream);

    wfrag_prep_kernel<<<NKT*NNT, 64, 0, stream>>>(tg_Wi, Wf_hi, Wf_lo);
    price_gru_kernel<<<NS, 192, 0, stream>>>(price, pg_Wi, pg_Wh, pg_bi, pg_bh, x_price);
    tweet_gru_kernel<<<NTt/TG, 256, 0, stream>>>(tweets, counts, Wf_hi, Wf_lo,
                                                 tg_Wh, tg_bi, tg_bh, news);
    date_gru_kernel<<<NS, 192, 0, stream>>>(news, dg_Wi, dg_Wh, dg_bi, dg_bh, text);
    bilinear_kernel<<<NS/BN, 256, 0, stream>>>(text, x_price, bil_A, bil_b, ft);
    deg_kernel<<<(Eq+255)/256, 256, 0, stream>>>(ei, deg);
    agg_kernel<<<(Eq*Hq)/256, 256, 0, stream>>>(ei, ft, agg);
    head_kernel<<<NS, 64, 0, stream>>>(ft, agg, deg,
                                       gnn_W, gnn_b, fc1_W, fc1_b, ln1_g, ln1_b,
                                       fc2_W, fc2_b, ln2_g, ln2_b,
                                       mlp_W1, mlp_b1, mlp_W2, mlp_b2,
                                       (float*)d_out);
}

// Round 3
// 939.734 us; speedup vs baseline: 2.2765x; 1.3308x over previous
//
#include <hip/hip_runtime.h>
#include <math.h>

#define Bq 8
#define Sq 500
#define Tq 30
#define Dq 5
#define Kq 10
#define Hq 64
#define TWq 512
#define Eq 8000
#define NS (Bq*Sq)      // 4000
#define NTt (NS*Dq)     // 20000
#define G3 (3*Hq)       // 192
#define TG 4            // tweet seqs per block

#define MR 48           // padded GEMM rows (TG*Kq=40 -> 48)
#define KC 64           // K chunk staged per iteration
#define XPITCH 72       // LDS row pitch in bf16 elems (144B: 2-way bank alias = free)
#define XGP 196         // xg fp32 pitch (196%32=4 -> conflict-free epilogue)
#define NKT (TWq/32)    // 16 k-tiles of 32
#define NNT (G3/16)     // 12 n-tiles of 16
#define PSEQ 16         // price seqs per block

typedef __attribute__((ext_vector_type(8))) short short8_t;
typedef __attribute__((ext_vector_type(4))) float float4_t;

__device__ __forceinline__ float fsig(float x) {
    return 1.0f / (1.0f + __expf(-x));
}
__device__ __forceinline__ float ftanh(float x) {
    // 1 - 2/(e^{2x}+1); exact limits at +-inf
    return 1.0f - 2.0f / (__expf(2.0f * x) + 1.0f);
}

__device__ __forceinline__ float wave_sum64(float v) {
    #pragma unroll
    for (int off = 32; off; off >>= 1) v += __shfl_xor(v, off, 64);
    return v;
}

__device__ __forceinline__ short f32_to_bf16_rn(float f) {
    union { float f; unsigned u; } v; v.f = f;
    unsigned r = v.u + 0x7fffu + ((v.u >> 16) & 1u);
    return (short)(r >> 16);
}
__device__ __forceinline__ float bf16_to_f32(short s) {
    union { unsigned u; float f; } v; v.u = ((unsigned)(unsigned short)s) << 16;
    return v.f;
}

// ---- prep: [K x 192] row-major -> MFMA B-frag order, split hi/lo bf16 ------
// Wf[kt][nt][lane][j] = W[kt*32 + (lane>>4)*8 + j][nt*16 + (lane&15)]
// grid = (K/32)*NNT blocks of 64
__global__ __launch_bounds__(64)
void wfrag_prep_kernel(const float* __restrict__ Wi,
                       short* __restrict__ Wf_hi, short* __restrict__ Wf_lo) {
    const int kt = blockIdx.x / NNT;
    const int nt = blockIdx.x - kt*NNT;
    const int lane = threadIdx.x;
    const int quad = lane >> 4, l16 = lane & 15;
    short h[8], l[8];
    #pragma unroll
    for (int j = 0; j < 8; j++) {
        int k = kt*32 + quad*8 + j;
        int n = nt*16 + l16;
        float w = Wi[(size_t)k*G3 + n];
        short hi = f32_to_bf16_rn(w);
        short lo = f32_to_bf16_rn(w - bf16_to_f32(hi));
        h[j] = hi; l[j] = lo;
    }
    size_t off = ((size_t)blockIdx.x*64 + lane)*8;
    *(short8_t*)(Wf_hi + off) = *(const short8_t*)h;
    *(short8_t*)(Wf_lo + off) = *(const short8_t*)l;
}

// ---- prep for bil_A: B[kidx][n] = bil_A[n*4096 + kidx]; grid 128*4 ---------
__global__ __launch_bounds__(64)
void bilfrag_prep_kernel(const float* __restrict__ A,
                         short* __restrict__ Bf_hi, short* __restrict__ Bf_lo) {
    const int kt = blockIdx.x >> 2;        // 0..127
    const int nt = blockIdx.x & 3;         // 0..3
    const int lane = threadIdx.x;
    const int quad = lane >> 4, l16 = lane & 15;
    short h[8], l[8];
    #pragma unroll
    for (int j = 0; j < 8; j++) {
        int kidx = kt*32 + quad*8 + j;
        int n = nt*16 + l16;
        float w = A[(size_t)n*4096 + kidx];
        short hi = f32_to_bf16_rn(w);
        h[j] = hi; l[j] = f32_to_bf16_rn(w - bf16_to_f32(hi));
    }
    size_t off = ((size_t)blockIdx.x*64 + lane)*8;
    *(short8_t*)(Bf_hi + off) = *(const short8_t*)h;
    *(short8_t*)(Bf_lo + off) = *(const short8_t*)l;
}

// -------- price GRU via MFMA: 16 seqs/block, gate-aligned n-tiles -----------
// wave w owns output units u = 16w + (lane&15); gates r/z/n come from
// n-tiles {w, 4+w, 8+w} so r,z,n land in the SAME lane -> no hg LDS trip.
__global__ __launch_bounds__(256)
void price_gru_mfma_kernel(const float* __restrict__ price,
                           const float* __restrict__ Wi,
                           const short* __restrict__ Whf_hi, const short* __restrict__ Whf_lo,
                           const float* __restrict__ bi, const float* __restrict__ bh,
                           float* __restrict__ xout) {
    __shared__ __align__(16) float price_s[PSEQ*90];
    __shared__ __align__(16) short h_hi[PSEQ*72];
    __shared__ __align__(16) short h_lo[PSEQ*72];
    const int tid = threadIdx.x;
    const int n0 = blockIdx.x * PSEQ;
    const int wv = tid >> 6;
    const int lane = tid & 63;
    const int quad = lane >> 4;
    const int l16 = lane & 15;
    const int u = wv*16 + l16;
    for (int i = tid; i < PSEQ*90; i += 256) price_s[i] = price[(size_t)n0*90 + i];
    for (int i = tid; i < PSEQ*72; i += 256) { h_hi[i] = 0; h_lo[i] = 0; }
    float wir[3], wiz[3], win[3];
    #pragma unroll
    for (int k = 0; k < 3; k++) {
        wir[k] = Wi[k*G3 + u];
        wiz[k] = Wi[k*G3 + 64 + u];
        win[k] = Wi[k*G3 + 128 + u];
    }
    const float cbr = bi[u] + bh[u];
    const float cbz = bi[64+u] + bh[64+u];
    const float bin = bi[128+u];
    const float bhn = bh[128+u];
    short8_t bfh[2][3], bfl[2][3];
    #pragma unroll
    for (int kt = 0; kt < 2; kt++)
        #pragma unroll
        for (int g = 0; g < 3; g++) {
            size_t off = (((size_t)kt*NNT + (g*4 + wv))*64 + lane)*8;
            bfh[kt][g] = *(const short8_t*)(Whf_hi + off);
            bfl[kt][g] = *(const short8_t*)(Whf_lo + off);
        }
    float hprev[4] = {0.f,0.f,0.f,0.f}, sum[4] = {0.f,0.f,0.f,0.f};
    __syncthreads();
    for (int t = 0; t < Tq; t++) {
        short8_t ah[2], al[2];
        #pragma unroll
        for (int kt = 0; kt < 2; kt++) {
            int addr = l16*72 + kt*32 + quad*8;
            ah[kt] = *(const short8_t*)&h_hi[addr];
            al[kt] = *(const short8_t*)&h_lo[addr];
        }
        float4_t accr = {0.f,0.f,0.f,0.f}, accz = {0.f,0.f,0.f,0.f}, accn = {0.f,0.f,0.f,0.f};
        #pragma unroll
        for (int kt = 0; kt < 2; kt++) {
            accr = __builtin_amdgcn_mfma_f32_16x16x32_bf16(ah[kt], bfh[kt][0], accr, 0,0,0);
            accr = __builtin_amdgcn_mfma_f32_16x16x32_bf16(ah[kt], bfl[kt][0], accr, 0,0,0);
            accr = __builtin_amdgcn_mfma_f32_16x16x32_bf16(al[kt], bfh[kt][0], accr, 0,0,0);
            accz = __builtin_amdgcn_mfma_f32_16x16x32_bf16(ah[kt], bfh[kt][1], accz, 0,0,0);
            accz = __builtin_amdgcn_mfma_f32_16x16x32_bf16(ah[kt], bfl[kt][1], accz, 0,0,0);
            accz = __builtin_amdgcn_mfma_f32_16x16x32_bf16(al[kt], bfh[kt][1], accz, 0,0,0);
            accn = __builtin_amdgcn_mfma_f32_16x16x32_bf16(ah[kt], bfh[kt][2], accn, 0,0,0);
            accn = __builtin_amdgcn_mfma_f32_16x16x32_bf16(ah[kt], bfl[kt][2], accn, 0,0,0);
            accn = __builtin_amdgcn_mfma_f32_16x16x32_bf16(al[kt], bfh[kt][2], accn, 0,0,0);
        }
        __syncthreads();   // A-frag reads done before h is rewritten
        #pragma unroll
        for (int r = 0; r < 4; r++) {
            const int s = quad*4 + r;
            float p0 = price_s[s*90 + t*3 + 0];
            float p1 = price_s[s*90 + t*3 + 1];
            float p2 = price_s[s*90 + t*3 + 2];
            float xr = fmaf(p2, wir[2], fmaf(p1, wir[1], fmaf(p0, wir[0], cbr)));
            float xz = fmaf(p2, wiz[2], fmaf(p1, wiz[1], fmaf(p0, wiz[0], cbz)));
            float xn = fmaf(p2, win[2], fmaf(p1, win[1], fmaf(p0, win[0], bin)));
            float rg = fsig(xr + accr[r]);
            float zg = fsig(xz + accz[r]);
            float ng = ftanh(xn + rg*(accn[r] + bhn));
            float h = (1.0f - zg)*ng + zg*hprev[r];
            hprev[r] = h; sum[r] += h;
            short hh = f32_to_bf16_rn(h);
            h_hi[s*72 + u] = hh;
            h_lo[s*72 + u] = f32_to_bf16_rn(h - bf16_to_f32(hh));
        }
        __syncthreads();   // h writes visible before next A-frag read
    }
    #pragma unroll
    for (int r = 0; r < 4; r++)
        xout[(size_t)(n0 + quad*4 + r)*Hq + u] = sum[r];
}

// ------------- tweet GRU: MFMA split-bf16 projection + fp32 recurrence ------
__global__ __launch_bounds__(256)
void tweet_gru_kernel(const float* __restrict__ tweets,
                      const int* __restrict__ counts,
                      const short* __restrict__ Wf_hi, const short* __restrict__ Wf_lo,
                      const float* __restrict__ Wh,
                      const float* __restrict__ bi, const float* __restrict__ bh,
                      float* __restrict__ news) {
    __shared__ __align__(16) char smem[MR*XGP*4];
    __shared__ __align__(16) float h_s[TG][Hq];
    __shared__ __align__(16) float hg_s[TG][XGP];
    __shared__ int len_s[TG];
    short* x_hi = (short*)smem;                       // MR*XPITCH shorts
    short* x_lo = (short*)(smem + MR*XPITCH*2);
    float* xg   = (float*)smem;                       // [MR][XGP], aliases staging

    const int tid  = threadIdx.x;
    const int n0   = blockIdx.x * TG;
    const int wave = tid >> 6;
    const int lane = tid & 63;
    const int quad = lane >> 4;
    const int l16  = lane & 15;

    if (tid < TG) {
        int c = counts[n0 + tid];
        len_s[tid] = c < 0 ? 0 : (c > Kq ? Kq : c);
    }

    float4_t acc[3][3];   // [mt][ntl]
    #pragma unroll
    for (int a = 0; a < 3; a++)
        #pragma unroll
        for (int b = 0; b < 3; b++)
            acc[a][b] = (float4_t){0.f, 0.f, 0.f, 0.f};

    for (int ch = 0; ch < TWq/KC; ch++) {
        __syncthreads();
        for (int i = tid; i < TG*Kq*(KC/4); i += 256) {
            int row = i >> 4;
            int c4  = i & 15;
            int s   = (row*205) >> 11;       // row/10 for row<48
            int t   = row - s*10;
            if (t < len_s[s]) {
                float4 v = *(const float4*)&tweets[(((size_t)(n0+s))*Kq + t)*TWq + ch*KC + c4*4];
                short hh[4], ll[4];
                float f[4] = {v.x, v.y, v.z, v.w};
                #pragma unroll
                for (int j = 0; j < 4; j++) {
                    short hi = f32_to_bf16_rn(f[j]);
                    hh[j] = hi;
                    ll[j] = f32_to_bf16_rn(f[j] - bf16_to_f32(hi));
                }
                *(short4*)&x_hi[row*XPITCH + c4*4] = *(const short4*)hh;
                *(short4*)&x_lo[row*XPITCH + c4*4] = *(const short4*)ll;
            }
        }
        __syncthreads();
        #pragma unroll
        for (int ks = 0; ks < KC/32; ks++) {
            const int kt = ch*(KC/32) + ks;
            short8_t bh_[3], bl_[3];
            #pragma unroll
            for (int ntl = 0; ntl < 3; ntl++) {
                size_t off = (((size_t)kt*NNT + (wave*3 + ntl))*64 + lane)*8;
                bh_[ntl] = *(const short8_t*)(Wf_hi + off);
                bl_[ntl] = *(const short8_t*)(Wf_lo + off);
            }
            short8_t ah_[3], al_[3];
            #pragma unroll
            for (int mt = 0; mt < 3; mt++) {
                int addr = (mt*16 + l16)*XPITCH + ks*32 + quad*8;
                ah_[mt] = *(const short8_t*)&x_hi[addr];
                al_[mt] = *(const short8_t*)&x_lo[addr];
            }
            #pragma unroll
            for (int mt = 0; mt < 3; mt++)
                #pragma unroll
                for (int ntl = 0; ntl < 3; ntl++) {
                    acc[mt][ntl] = __builtin_amdgcn_mfma_f32_16x16x32_bf16(ah_[mt], bh_[ntl], acc[mt][ntl], 0, 0, 0);
                    acc[mt][ntl] = __builtin_amdgcn_mfma_f32_16x16x32_bf16(ah_[mt], bl_[ntl], acc[mt][ntl], 0, 0, 0);
                    acc[mt][ntl] = __builtin_amdgcn_mfma_f32_16x16x32_bf16(al_[mt], bh_[ntl], acc[mt][ntl], 0, 0, 0);
                }
        }
    }
    __syncthreads();       // all A-frag reads done before xg overwrites staging
    #pragma unroll
    for (int ntl = 0; ntl < 3; ntl++) {
        const int col = (wave*3 + ntl)*16 + l16;
        const float bic = bi[col];
        #pragma unroll
        for (int mt = 0; mt < 3; mt++) {
            const int row0 = mt*16 + quad*4;
            #pragma unroll
            for (int r = 0; r < 4; r++)
                xg[(row0 + r)*XGP + col] = acc[mt][ntl][r] + bic;
        }
    }
    // ---- recurrence (fp32) ----
    const int g = tid;
    float w[Hq];
    if (tid < G3) {
        #pragma unroll
        for (int j = 0; j < Hq; j++) w[j] = Wh[(size_t)j*G3 + g];
    }
    const float bhg = (tid < G3) ? bh[g] : 0.0f;
    const int su_s = tid >> 6;
    const int su_u = tid & 63;
    h_s[su_s][su_u] = 0.0f;
    float hreg = 0.0f, sum = 0.0f;
    __syncthreads();
    for (int t = 0; t < Kq; t++) {
        if (tid < G3) {
            #pragma unroll
            for (int s = 0; s < TG; s++) {
                if (t < len_s[s]) {
                    float a0=0.f,a1=0.f,a2=0.f,a3=0.f;
                    #pragma unroll
                    for (int j = 0; j < Hq; j += 4) {
                        float4 hv = *(const float4*)&h_s[s][j];
                        a0 = fmaf(hv.x, w[j+0], a0);
                        a1 = fmaf(hv.y, w[j+1], a1);
                        a2 = fmaf(hv.z, w[j+2], a2);
                        a3 = fmaf(hv.w, w[j+3], a3);
                    }
                    hg_s[s][g] = bhg + ((a0+a1)+(a2+a3));
                }
            }
        }
        __syncthreads();
        if (t < len_s[su_s]) {
            const float* xr = &xg[(su_s*Kq + t)*XGP];
            float r  = fsig(xr[su_u]        + hg_s[su_s][su_u]);
            float z  = fsig(xr[Hq+su_u]     + hg_s[su_s][Hq+su_u]);
            float nn = ftanh(xr[2*Hq+su_u] + r*hg_s[su_s][2*Hq+su_u]);
            hreg = (1.0f - z)*nn + z*hreg;
            sum += hreg;
            h_s[su_s][su_u] = hreg;
        }
        __syncthreads();
    }
    news[(size_t)(n0 + su_s)*Hq + su_u] = sum;
}

// ---------------- date GRU: one block (192 thr) per sequence ----------------
__global__ __launch_bounds__(192)
void date_gru_kernel(const float* __restrict__ news,
                     const float* __restrict__ Wi, const float* __restrict__ Wh,
                     const float* __restrict__ bi, const float* __restrict__ bh,
                     float* __restrict__ text) {
    __shared__ __align__(16) float nw_s[Dq*Hq];
    __shared__ __align__(16) float h_s[Hq];
    __shared__ __align__(16) float xg_s[G3];
    __shared__ __align__(16) float hg_s[G3];
    const int n = blockIdx.x;
    const int g = threadIdx.x;
    for (int i = g; i < Dq*Hq; i += 192) nw_s[i] = news[(size_t)n*Dq*Hq + i];
    float wi[Hq], wh[Hq];
    #pragma unroll
    for (int j = 0; j < Hq; j++) { wi[j] = Wi[j*G3+g]; wh[j] = Wh[j*G3+g]; }
    const float big = bi[g], bhg = bh[g];
    if (g < Hq) h_s[g] = 0.0f;
    float hreg = 0.0f, sum = 0.0f;
    __syncthreads();
    for (int t = 0; t < Dq; t++) {
        float a0=0.f,a1=0.f,a2=0.f,a3=0.f, b0=0.f,b1=0.f,b2=0.f,b3=0.f;
        #pragma unroll
        for (int j = 0; j < Hq; j += 4) {
            float4 nv = *(const float4*)&nw_s[t*Hq + j];
            float4 hv = *(const float4*)&h_s[j];
            a0 = fmaf(nv.x, wi[j+0], a0);
            a1 = fmaf(nv.y, wi[j+1], a1);
            a2 = fmaf(nv.z, wi[j+2], a2);
            a3 = fmaf(nv.w, wi[j+3], a3);
            b0 = fmaf(hv.x, wh[j+0], b0);
            b1 = fmaf(hv.y, wh[j+1], b1);
            b2 = fmaf(hv.z, wh[j+2], b2);
            b3 = fmaf(hv.w, wh[j+3], b3);
        }
        xg_s[g] = big + ((a0+a1)+(a2+a3));
        hg_s[g] = bhg + ((b0+b1)+(b2+b3));
        __syncthreads();
        if (g < Hq) {
            float r  = fsig(xg_s[g]      + hg_s[g]);
            float z  = fsig(xg_s[Hq+g]   + hg_s[Hq+g]);
            float nn = ftanh(xg_s[2*Hq+g] + r*hg_s[2*Hq+g]);
            hreg = (1.0f - z)*nn + z*hreg;
            sum += hreg;
            h_s[g] = hreg;
        }
        __syncthreads();
    }
    if (g < Hq) text[(size_t)n*Hq + g] = sum;
}

// -------- bilinear via MFMA: C[n,k] = tanh(sum_ij P[n,ij] A2[k,ij] + b_k) ---
#define TP 68
#define XP 72
__global__ __launch_bounds__(256)
void bilinear_mfma_kernel(const float* __restrict__ text, const float* __restrict__ x,
                          const short* __restrict__ Bf_hi, const short* __restrict__ Bf_lo,
                          const float* __restrict__ bb, float* __restrict__ ft) {
    __shared__ __align__(16) float t_s[16*TP];
    __shared__ __align__(16) float x_s[16*XP];
    const int tid = threadIdx.x;
    const int n0 = blockIdx.x * 16;
    const int wv = tid >> 6, lane = tid & 63, quad = lane >> 4, l16 = lane & 15;
    for (int i = tid; i < 16*64; i += 256) {
        int r = i >> 6, c = i & 63;
        t_s[r*TP + c] = text[(size_t)(n0 + r)*Hq + c];
        x_s[r*XP + c] = x[(size_t)(n0 + r)*Hq + c];
    }
    float4_t acc = {0.f,0.f,0.f,0.f};
    __syncthreads();
    for (int kt = 0; kt < 128; kt++) {
        const int i  = kt >> 1;
        const int j0 = (kt & 1)*32 + quad*8;
        size_t boff = (((size_t)kt*4 + wv)*64 + lane)*8;
        short8_t bh_ = *(const short8_t*)(Bf_hi + boff);
        short8_t bl_ = *(const short8_t*)(Bf_lo + boff);
        float ti = t_s[l16*TP + i];
        float xv[8];
        *(float4*)&xv[0] = *(const float4*)&x_s[l16*XP + j0];
        *(float4*)&xv[4] = *(const float4*)&x_s[l16*XP + j0 + 4];
        short ph[8], pl[8];
        #pragma unroll
        for (int jj = 0; jj < 8; jj++) {
            float p = ti * xv[jj];
            short hi = f32_to_bf16_rn(p);
            ph[jj] = hi;
            pl[jj] = f32_to_bf16_rn(p - bf16_to_f32(hi));
        }
        short8_t ah = *(const short8_t*)ph;
        short8_t al = *(const short8_t*)pl;
        acc = __builtin_amdgcn_mfma_f32_16x16x32_bf16(ah, bh_, acc, 0,0,0);
        acc = __builtin_amdgcn_mfma_f32_16x16x32_bf16(ah, bl_, acc, 0,0,0);
        acc = __builtin_amdgcn_mfma_f32_16x16x32_bf16(al, bh_, acc, 0,0,0);
    }
    const int col = wv*16 + l16;
    const float bk = bb[col];
    #pragma unroll
    for (int r = 0; r < 4; r++) {
        int n = quad*4 + r;
        ft[(size_t)(n0 + n)*Hq + col] = ftanh(acc[r] + bk);
    }
}

// ----------------------------- GNN ------------------------------------------
__global__ void deg_kernel(const int* __restrict__ ei, float* __restrict__ deg) {
    int e = blockIdx.x*256 + threadIdx.x;
    if (e < Eq) atomicAdd(&deg[ei[Eq + e]], 1.0f);
}

__global__ void agg_kernel(const int* __restrict__ ei, const float* __restrict__ ft,
                           float* __restrict__ agg) {
    int gid = blockIdx.x*256 + threadIdx.x;
    int e = gid >> 6;
    int u = gid & 63;
    if (e < Eq) {
        int src = ei[e], dst = ei[Eq + e];
        #pragma unroll
        for (int b = 0; b < Bq; b++) {
            atomicAdd(&agg[((size_t)(b*Sq + dst))*Hq + u],
                      ft[((size_t)(b*Sq + src))*Hq + u]);
        }
    }
}

// ------------------------------ head ----------------------------------------
__global__ __launch_bounds__(64)
void head_kernel(const float* __restrict__ ft, const float* __restrict__ agg,
                 const float* __restrict__ deg,
                 const float* __restrict__ gnn_W, const float* __restrict__ gnn_b,
                 const float* __restrict__ fc1_W, const float* __restrict__ fc1_b,
                 const float* __restrict__ ln1_g, const float* __restrict__ ln1_b,
                 const float* __restrict__ fc2_W, const float* __restrict__ fc2_b,
                 const float* __restrict__ ln2_g, const float* __restrict__ ln2_b,
                 const float* __restrict__ mlp_W1, const float* __restrict__ mlp_b1,
                 const float* __restrict__ mlp_W2, const float* __restrict__ mlp_b2,
                 float* __restrict__ out) {
    __shared__ __align__(16) float a_s[Hq];
    __shared__ __align__(16) float in_s[2*Hq];
    __shared__ __align__(16) float t_s[Hq];
    const int n = blockIdx.x;
    const int s = n % Sq;
    const int u = threadIdx.x;
    const float denom = fmaxf(deg[s], 1.0f);
    a_s[u]  = agg[(size_t)n*Hq + u] / denom;
    in_s[u] = ft[(size_t)n*Hq + u];
    __syncthreads();
    {
        float a0=0.f,a1=0.f,a2=0.f,a3=0.f;
        #pragma unroll
        for (int j = 0; j < Hq; j += 4) {
            a0 = fmaf(a_s[j+0], gnn_W[(j+0)*Hq + u], a0);
            a1 = fmaf(a_s[j+1], gnn_W[(j+1)*Hq + u], a1);
            a2 = fmaf(a_s[j+2], gnn_W[(j+2)*Hq + u], a2);
            a3 = fmaf(a_s[j+3], gnn_W[(j+3)*Hq + u], a3);
        }
        in_s[Hq+u] = ftanh(gnn_b[u] + ((a0+a1)+(a2+a3)));
    }
    __syncthreads();
    float v;
    {
        float a0=0.f,a1=0.f,a2=0.f,a3=0.f;
        #pragma unroll
        for (int j = 0; j < 2*Hq; j += 4) {
            a0 = fmaf(in_s[j+0], fc1_W[(j+0)*Hq + u], a0);
            a1 = fmaf(in_s[j+1], fc1_W[(j+1)*Hq + u], a1);
            a2 = fmaf(in_s[j+2], fc1_W[(j+2)*Hq + u], a2);
            a3 = fmaf(in_s[j+3], fc1_W[(j+3)*Hq + u], a3);
        }
        v = fc1_b[u] + ((a0+a1)+(a2+a3));
        float m = wave_sum64(v) * (1.0f/Hq);
        float d = v - m;
        float var = wave_sum64(d*d) * (1.0f/Hq);
        v = fmaxf(d * rsqrtf(var + 1e-5f) * ln1_g[u] + ln1_b[u], 0.0f);
    }
    t_s[u] = v;
    __syncthreads();
    {
        float a0=0.f,a1=0.f,a2=0.f,a3=0.f;
        #pragma unroll
        for (int j = 0; j < Hq; j += 4) {
            a0 = fmaf(t_s[j+0], fc2_W[(j+0)*Hq + u], a0);
            a1 = fmaf(t_s[j+1], fc2_W[(j+1)*Hq + u], a1);
            a2 = fmaf(t_s[j+2], fc2_W[(j+2)*Hq + u], a2);
            a3 = fmaf(t_s[j+3], fc2_W[(j+3)*Hq + u], a3);
        }
        v = fc2_b[u] + ((a0+a1)+(a2+a3));
        float m = wave_sum64(v) * (1.0f/Hq);
        float d = v - m;
        float var = wave_sum64(d*d) * (1.0f/Hq);
        v = fmaxf(d * rsqrtf(var + 1e-5f) * ln2_g[u] + ln2_b[u], 0.0f);
    }
    __syncthreads();
    a_s[u] = v;
    __syncthreads();
    {
        float a0=0.f,a1=0.f,a2=0.f,a3=0.f;
        #pragma unroll
        for (int j = 0; j < Hq; j += 4) {
            a0 = fmaf(a_s[j+0], mlp_W1[(j+0)*Hq + u], a0);
            a1 = fmaf(a_s[j+1], mlp_W1[(j+1)*Hq + u], a1);
            a2 = fmaf(a_s[j+2], mlp_W1[(j+2)*Hq + u], a2);
            a3 = fmaf(a_s[j+3], mlp_W1[(j+3)*Hq + u], a3);
        }
        v = fmaxf(mlp_b1[u] + ((a0+a1)+(a2+a3)), 0.0f);
    }
    float p = wave_sum64(v * mlp_W2[u]);
    if (u == 0) out[n] = p + mlp_b2[0];
}

extern "C" void kernel_launch(void* const* d_in, const int* in_sizes, int n_in,
                              void* d_out, int out_size, void* d_ws, size_t ws_size,
                              hipStream_t stream) {
    (void)in_sizes; (void)n_in; (void)out_size; (void)ws_size;
    const float* price  = (const float*)d_in[0];
    const float* tweets = (const float*)d_in[1];
    const int*   counts = (const int*)d_in[2];
    const int*   ei     = (const int*)d_in[3];
    const float* pg_Wi = (const float*)d_in[5];
    const float* pg_Wh = (const float*)d_in[6];
    const float* pg_bi = (const float*)d_in[7];
    const float* pg_bh = (const float*)d_in[8];
    const float* tg_Wi = (const float*)d_in[9];
    const float* tg_Wh = (const float*)d_in[10];
    const float* tg_bi = (const float*)d_in[11];
    const float* tg_bh = (const float*)d_in[12];
    const float* dg_Wi = (const float*)d_in[13];
    const float* dg_Wh = (const float*)d_in[14];
    const float* dg_bi = (const float*)d_in[15];
    const float* dg_bh = (const float*)d_in[16];
    const float* bil_A = (const float*)d_in[17];
    const float* bil_b = (const float*)d_in[18];
    const float* gnn_W = (const float*)d_in[19];
    const float* gnn_b = (const float*)d_in[20];
    const float* fc1_W = (const float*)d_in[21];
    const float* fc1_b = (const float*)d_in[22];
    const float* ln1_g = (const float*)d_in[23];
    const float* ln1_b = (const float*)d_in[24];
    const float* fc2_W = (const float*)d_in[25];
    const float* fc2_b = (const float*)d_in[26];
    const float* ln2_g = (const float*)d_in[27];
    const float* ln2_b = (const float*)d_in[28];
    const float* mlp_W1 = (const float*)d_in[29];
    const float* mlp_b1 = (const float*)d_in[30];
    const float* mlp_W2 = (const float*)d_in[31];
    const float* mlp_b2 = (const float*)d_in[32];

    float* ws      = (float*)d_ws;
    float* x_price = ws;                   // 4000*64   = 256000
    float* news    = ws + 256000;          // 20000*64  = 1280000
    float* text    = ws + 1536000;         // 4000*64
    float* ft      = ws + 1792000;         // 4000*64
    float* agg     = ws + 2048000;         // 8*500*64  = 256000
    float* deg     = ws + 2304000;         // 512
    short* Wf_hi   = (short*)(ws + 2304512);           // 98304 shorts
    short* Wf_lo   = Wf_hi  + 98304;
    short* Whp_hi  = Wf_lo  + 98304;                   // 2*12*64*8 = 12288
    short* Whp_lo  = Whp_hi + 12288;
    short* Bf_hi   = Whp_lo + 12288;                   // 512*64*8 = 262144
    short* Bf_lo   = Bf_hi  + 262144;

    hipMemsetAsync(agg, 0, (256000 + 512)*sizeof(float), stream);

    wfrag_prep_kernel<<<NKT*NNT, 64, 0, stream>>>(tg_Wi, Wf_hi, Wf_lo);
    wfrag_prep_kernel<<<2*NNT, 64, 0, stream>>>(pg_Wh, Whp_hi, Whp_lo);
    bilfrag_prep_kernel<<<128*4, 64, 0, stream>>>(bil_A, Bf_hi, Bf_lo);

    price_gru_mfma_kernel<<<NS/PSEQ, 256, 0, stream>>>(price, pg_Wi, Whp_hi, Whp_lo,
                                                       pg_bi, pg_bh, x_price);
    tweet_gru_kernel<<<NTt/TG, 256, 0, stream>>>(tweets, counts, Wf_hi, Wf_lo,
                                                 tg_Wh, tg_bi, tg_bh, news);
    date_gru_kernel<<<NS, 192, 0, stream>>>(news, dg_Wi, dg_Wh, dg_bi, dg_bh, text);
    bilinear_mfma_kernel<<<NS/16, 256, 0, stream>>>(text, x_price, Bf_hi, Bf_lo, bil_b, ft);
    deg_kernel<<<(Eq+255)/256, 256, 0, stream>>>(ei, deg);
    agg_kernel<<<(Eq*Hq)/256, 256, 0, stream>>>(ei, ft, agg);
    head_kernel<<<NS, 64, 0, stream>>>(ft, agg, deg,
                                       gnn_W, gnn_b, fc1_W, fc1_b, ln1_g, ln1_b,
                                       fc2_W, fc2_b, ln2_g, ln2_b,
                                       mlp_W1, mlp_b1, mlp_W2, mlp_b2,
                                       (float*)d_out);
}